// Round 8
// baseline (297.266 us; speedup 1.0000x reference)
//
#include <hip/hip_runtime.h>

typedef short short8 __attribute__((ext_vector_type(8)));
typedef float f32x4 __attribute__((ext_vector_type(4)));
typedef unsigned short u16;
typedef u16 u16x8 __attribute__((ext_vector_type(8)));
typedef u16 u16x4 __attribute__((ext_vector_type(4)));

__device__ static inline u16 f2bf(float f) {
    union { float f; unsigned u; } v; v.f = f;
    unsigned r = v.u + 0x7fffu + ((v.u >> 16) & 1u);
    return (u16)(r >> 16);
}

// packed f32x2 -> bf16x2 (RNE), low16 = cvt(a), high16 = cvt(b)
__device__ static inline unsigned cvt_pk_bf16(float a, float b) {
    unsigned r;
    asm("v_cvt_pk_bf16_f32 %0, %1, %2" : "=v"(r) : "v"(a), "v"(b));
    return r;
}

// attn block map: u -> (J<<2)|(half<<1)|split. 24 blocks per (h,comp);
// J<8 full blocks, J>=8 split into two key-halves. Triples {u, u+8, u+16}
// (co-resident on one CU) each sum to exactly 34 kt-tiles.
__constant__ unsigned char ATT_MAP[24] = {
    61, 28, 57, 59, 55, 24, 20, 45,   // slot 0
    63, 53, 49, 41, 16, 43, 51, 47,   // slot 1
     0,  4,  8, 12, 37, 33, 39, 35};  // slot 2

// ---------------- fused cast fp32 -> bf16 for x / W_qkv / W_o --------------------
__global__ __launch_bounds__(256) void cast3_kernel(const float* __restrict__ xa,
                                                    u16* __restrict__ xo,
                                                    const float* __restrict__ wa,
                                                    u16* __restrict__ wo,
                                                    const float* __restrict__ oa,
                                                    u16* __restrict__ oo) {
    const int bid = blockIdx.x;
    const float* in;
    u16* out;
    int b;
    if (bid < 4096)        { in = xa; out = xo; b = bid; }
    else if (bid < 16384)  { in = wa; out = wo; b = bid - 4096; }
    else                   { in = oa; out = oo; b = bid - 16384; }
    int i = (b * 256 + threadIdx.x) * 4;
    f32x4 v = *(const f32x4*)&in[i];
    union { unsigned w[2]; u16x4 s; } o;
    o.w[0] = cvt_pk_bf16(v[0], v[1]);
    o.w[1] = cvt_pk_bf16(v[2], v[3]);
    *(u16x4*)&out[i] = o.s;
}

// ---------------- GEMM: C = A(MxK) * B(NxK)^T, bf16 in, fp32 acc ----------------
// Register-staged prefetch + XOR bank-swizzle. LDS double-buffered so only ONE
// __syncthreads (one vmcnt/lgkm drain) per K-step instead of two: write buf[p]
// -> barrier -> read buf[p] while next iter writes buf[p^1]. Reads of buf[p]
// complete (lgkm before MFMA) before any wave passes the next barrier, so the
// t+2 write to the same buffer is race-free.
template <int BM, int BN, int MODE, int MINW>
__global__ __launch_bounds__(256, MINW) void gemm_bt(const u16* __restrict__ A,
                                                     const u16* __restrict__ B,
                                                     int M, int N, int K,
                                                     float* __restrict__ C,
                                                     u16* __restrict__ Qo,
                                                     u16* __restrict__ Ko,
                                                     u16* __restrict__ Vo) {
    constexpr int APT = BM * 4 / 256;
    constexpr int BPT = BN * 4 / 256;
    constexpr int MT = BM / 32, NT = BN / 32;
    __shared__ u16 As[2][BM * 32];
    __shared__ u16 Bs[2][BN * 32];
    const int tid  = threadIdx.x;
    const int lane = tid & 63, wave = tid >> 6;
    const int quad = lane >> 4, l15 = lane & 15;
    const int wm = wave >> 1, wn = wave & 1;
    const int m0 = blockIdx.y * BM;
    const int n0 = blockIdx.x * BN;

    f32x4 acc[MT][NT] = {};

    const u16* aga[APT];
    const u16* bga[BPT];
#pragma unroll
    for (int i = 0; i < APT; i++) {
        int s = tid + i * 256, r = s >> 2;
        int kg = (s & 3) ^ ((r >> 1) & 3);
        aga[i] = &A[(size_t)(m0 + r) * K + kg * 8];
    }
#pragma unroll
    for (int i = 0; i < BPT; i++) {
        int s = tid + i * 256, r = s >> 2;
        int kg = (s & 3) ^ ((r >> 1) & 3);
        bga[i] = &B[(size_t)(n0 + r) * K + kg * 8];
    }

    u16x8 ast[APT], bst[BPT];
#pragma unroll
    for (int i = 0; i < APT; i++) ast[i] = *(const u16x8*)aga[i];
#pragma unroll
    for (int i = 0; i < BPT; i++) bst[i] = *(const u16x8*)bga[i];

    for (int k0 = 0; k0 < K; k0 += 32) {
        const int p = (k0 >> 5) & 1;
#pragma unroll
        for (int i = 0; i < APT; i++) *(u16x8*)&As[p][(tid + i * 256) * 8] = ast[i];
#pragma unroll
        for (int i = 0; i < BPT; i++) *(u16x8*)&Bs[p][(tid + i * 256) * 8] = bst[i];
        __syncthreads();
        if (k0 + 32 < K) {
#pragma unroll
            for (int i = 0; i < APT; i++) ast[i] = *(const u16x8*)(aga[i] + k0 + 32);
#pragma unroll
            for (int i = 0; i < BPT; i++) bst[i] = *(const u16x8*)(bga[i] + k0 + 32);
        }

        short8 af[MT], bf[NT];
#pragma unroll
        for (int mt = 0; mt < MT; mt++) {
            int row = wm * (BM / 2) + mt * 16 + l15;
            int slot = row * 4 + (quad ^ ((row >> 1) & 3));
            af[mt] = *(const short8*)&As[p][slot * 8];
        }
#pragma unroll
        for (int nt = 0; nt < NT; nt++) {
            int row = wn * (BN / 2) + nt * 16 + l15;
            int slot = row * 4 + (quad ^ ((row >> 1) & 3));
            bf[nt] = *(const short8*)&Bs[p][slot * 8];
        }
#pragma unroll
        for (int mt = 0; mt < MT; mt++)
#pragma unroll
            for (int nt = 0; nt < NT; nt++)
                acc[mt][nt] = __builtin_amdgcn_mfma_f32_16x16x32_bf16(af[mt], bf[nt], acc[mt][nt], 0, 0, 0);
    }

    if (MODE == 0) {
#pragma unroll
        for (int mt = 0; mt < MT; mt++)
#pragma unroll
            for (int nt = 0; nt < NT; nt++)
#pragma unroll
                for (int r = 0; r < 4; r++) {
                    int row = m0 + wm * (BM / 2) + mt * 16 + quad * 4 + r;
                    int col = n0 + wn * (BN / 2) + nt * 16 + l15;
                    C[(size_t)row * N + col] = acc[mt][nt][r];
                }
    } else {
        const int comp = n0 >> 11, h = (n0 >> 7) & 15;
        u16* dst = (comp == 0) ? Qo : ((comp == 1) ? Ko : Vo);
        const float sc = (comp == 0) ? 0.18033688f : 1.0f;  // 0.125*log2(e)
#pragma unroll
        for (int mt = 0; mt < MT; mt++)
#pragma unroll
            for (int nt = 0; nt < NT; nt++)
#pragma unroll
                for (int r = 0; r < 4; r++) {
                    int row = m0 + wm * (BM / 2) + mt * 16 + quad * 4 + r;
                    int d = wn * (BN / 2) + nt * 16 + l15;
                    dst[((h * 2048) + row) * 128 + d] = f2bf(acc[mt][nt][r] * sc);
                }
    }
}

// ---------------- per-head V transpose: vb[h][s][d] -> vT[h][d][s] ----------------
__global__ __launch_bounds__(256) void transpose_v(const u16* __restrict__ vb,
                                                   u16* __restrict__ vT) {
    __shared__ u16 T[64 * 136];
    const int s0 = blockIdx.x * 64, h = blockIdx.y;
    const int tid = threadIdx.x;
#pragma unroll
    for (int i = 0; i < 4; i++) {
        int c = tid + i * 256;
        int s = c >> 4, dch = c & 15;
        *(u16x8*)&T[s * 136 + dch * 8] =
            *(const u16x8*)&vb[((h * 2048) + s0 + s) * 128 + dch * 8];
    }
    __syncthreads();
#pragma unroll
    for (int i = 0; i < 4; i++) {
        int c = tid + i * 256;
        int d = c >> 3, sch = c & 7;
        u16x8 o;
#pragma unroll
        for (int j = 0; j < 8; j++) o[j] = T[(sch * 8 + j) * 136 + d];
        *(u16x8*)&vT[((h * 128) + d) * 2048 + s0 + sch * 8] = o;
    }
}

// ---------------- flash attention, S^T formulation, key-split ------------------
// 768 blocks: h (low 4 bits, XCD-pinned L2), comp, u -> ATT_MAP -> (J, half,
// split). J<8: full block, normalized in-kernel. J>=8: two key-halves writing
// UNNORMALIZED partial O^T + row-sums l (max-free softmax => associative).
// K/V LDS double-buffered: ONE barrier per kt (same proof as gemm_bt).
// launch_bounds floor stays 2 (round 6: floor 3 spills the accumulator).
__global__ __launch_bounds__(256, 2) void attn_kernel(const u16* __restrict__ qb,
                                                      const u16* __restrict__ kb,
                                                      const u16* __restrict__ vT,
                                                      float* __restrict__ ob,
                                                      float* __restrict__ op1,
                                                      float* __restrict__ lb0,
                                                      float* __restrict__ lb1) {
    const int bid = blockIdx.x;
    const int h = bid & 15;
    const int comp = (bid >> 4) & 1;
    const int u = bid >> 5;  // 0..23
    const int e = ATT_MAP[u];
    const int J = e >> 2, half = (e >> 1) & 1, split = e & 1;
    const int nkt = 2 * J + 2;
    const int kt0 = (split && half) ? (J + 1) : 0;
    const int kt1 = (split && !half) ? (J + 1) : nkt;
    const int q0 = J * 128;
    const int tid = threadIdx.x, lane = tid & 63, wave = tid >> 6;
    const int quad = lane >> 4, l15 = lane & 15;
    const int qh = quad >> 1, ql = quad & 1;

    __shared__ u16 Ks[2][64 * 64];    // [key][dim-chunk swizzled]  (this comp)
    __shared__ u16 VsT[2][128 * 64];  // [dim][key-chunk swizzled]

    const u16* kb_h = &kb[(size_t)h * 2048 * 128 + comp * 64];
    const u16* vT_h = &vT[(size_t)h * 128 * 2048];

    // staging global addresses
    const int c1 = tid, c2 = tid + 256;
    const int k1key = c1 >> 3, k1dc = ((c1 & 7) ^ k1key) & 7;
    const int k2key = c2 >> 3, k2dc = ((c2 & 7) ^ k2key) & 7;
    const u16* kaddr1 = &kb_h[k1key * 128 + k1dc * 8];
    const u16* kaddr2 = &kb_h[k2key * 128 + k2dc * 8];
    const u16* vaddr[4];
#pragma unroll
    for (int i = 0; i < 4; i++) {
        int c = tid + i * 256;
        int dim = c >> 3, kc = ((c & 7) ^ dim) & 7;
        vaddr[i] = &vT_h[dim * 2048 + kc * 8];
    }

    // loop-invariant LDS read byte-offsets.
    const int koff0 = l15 * 128 + ((quad ^ l15) & 7) * 16;
    const int koff1 = l15 * 128 + (((quad + 4) ^ l15) & 7) * 16;
    int vbo[8][2];
#pragma unroll
    for (int nt = 0; nt < 8; nt++) {
        int dim = nt * 16 + l15;
        int base = dim * 128 + ((qh ^ dim) & 7) * 16 + ql * 8;
        vbo[nt][0] = base;
        vbo[nt][1] = base ^ 64;
    }

    // Q fragments as MFMA B-operand: B[n=q=l15][k=dim=quad*8+j]
    short8 aq[2][2];
#pragma unroll
    for (int qs = 0; qs < 2; qs++)
#pragma unroll
        for (int ks = 0; ks < 2; ks++) {
            int qrow = q0 + wave * 32 + qs * 16 + l15;
            aq[qs][ks] = *(const short8*)
                &qb[((h * 2048) + qrow) * 128 + comp * 64 + ks * 32 + quad * 8];
        }

    float l_acc[2] = {0.f, 0.f};
    f32x4 acc[8][2] = {};  // O^T: [dim-tile nt][q-subtile]; rows=dim, cols=q

    u16x8 kst0, kst1, vst[4];
    kst0 = *(const u16x8*)(kaddr1 + kt0 * 8192);
    kst1 = *(const u16x8*)(kaddr2 + kt0 * 8192);
#pragma unroll
    for (int i = 0; i < 4; i++) vst[i] = *(const u16x8*)(vaddr[i] + kt0 * 64);
    const u16* kp1 = kaddr1 + (kt0 + 1) * 8192;
    const u16* kp2 = kaddr2 + (kt0 + 1) * 8192;
    const u16* vp[4];
#pragma unroll
    for (int i = 0; i < 4; i++) vp[i] = vaddr[i] + (kt0 + 1) * 64;

    for (int kt = kt0; kt < kt1; kt++) {
        const int p = kt & 1;
        *(u16x8*)&Ks[p][c1 * 8] = kst0;
        *(u16x8*)&Ks[p][c2 * 8] = kst1;
#pragma unroll
        for (int i = 0; i < 4; i++) *(u16x8*)&VsT[p][(tid + i * 256) * 8] = vst[i];
        __syncthreads();
        const char* KsB = (const char*)Ks[p];
        const char* VsB = (const char*)VsT[p];

        if (kt + 1 < kt1) {
            kst0 = *(const u16x8*)kp1; kp1 += 8192;
            kst1 = *(const u16x8*)kp2; kp2 += 8192;
#pragma unroll
            for (int i = 0; i < 4; i++) { vst[i] = *(const u16x8*)vp[i]; vp[i] += 64; }
        }

        // K fragments once per tile (shared by both q-subtiles)
        short8 kf[4][2];
#pragma unroll
        for (int kn = 0; kn < 4; kn++) {
            kf[kn][0] = *(const short8*)(KsB + (koff0 + kn * 2048));
            kf[kn][1] = *(const short8*)(KsB + (koff1 + kn * 2048));
        }

        // S^T = K*Q^T; exponentiate in-register; pack FULL-K PV B-fragments
        short8 b8[2][2];  // [qs][kn2]: slots 0..3 <- kn=2kn2, 4..7 <- kn=2kn2+1
#pragma unroll
        for (int qs = 0; qs < 2; qs++) {
#pragma unroll
            for (int kn2 = 0; kn2 < 2; kn2++) {
                f32x4 sa = {}, sb = {};
                sa = __builtin_amdgcn_mfma_f32_16x16x32_bf16(kf[2 * kn2][0], aq[qs][0], sa, 0, 0, 0);
                sa = __builtin_amdgcn_mfma_f32_16x16x32_bf16(kf[2 * kn2][1], aq[qs][1], sa, 0, 0, 0);
                sb = __builtin_amdgcn_mfma_f32_16x16x32_bf16(kf[2 * kn2 + 1][0], aq[qs][0], sb, 0, 0, 0);
                sb = __builtin_amdgcn_mfma_f32_16x16x32_bf16(kf[2 * kn2 + 1][1], aq[qs][1], sb, 0, 0, 0);
                if (kt >= nkt - 2) {  // diagonal region: causal mask
                    int q = q0 + wave * 32 + qs * 16 + l15;
                    int kb0 = kt * 64 + kn2 * 32 + quad * 4;
#pragma unroll
                    for (int r = 0; r < 4; r++) {
                        if (kb0 + r > q) sa[r] = -1e30f;
                        if (kb0 + 16 + r > q) sb[r] = -1e30f;
                    }
                }
                float p0 = exp2f(sa[0]), p1 = exp2f(sa[1]), p2 = exp2f(sa[2]), p3 = exp2f(sa[3]);
                float p4 = exp2f(sb[0]), p5 = exp2f(sb[1]), p6 = exp2f(sb[2]), p7 = exp2f(sb[3]);
                l_acc[qs] += ((p0 + p1) + (p2 + p3)) + ((p4 + p5) + (p6 + p7));
                union { unsigned w[4]; short8 s; } pw;
                pw.w[0] = cvt_pk_bf16(p0, p1);
                pw.w[1] = cvt_pk_bf16(p2, p3);
                pw.w[2] = cvt_pk_bf16(p4, p5);
                pw.w[3] = cvt_pk_bf16(p6, p7);
                b8[qs][kn2] = pw.s;
            }
        }

        // PV: O^T[d][q] += V^T * P^T, full-K (32 keys per MFMA).
        __builtin_amdgcn_s_setprio(1);
#pragma unroll
        for (int nt = 0; nt < 8; nt++) {
#pragma unroll
            for (int kn2 = 0; kn2 < 2; kn2++) {
                union { u16x4 h4[2]; short8 s; } av;
                int o0 = vbo[nt][kn2];
                av.h4[0] = *(const u16x4*)(VsB + o0);         // keys of kn=2kn2
                av.h4[1] = *(const u16x4*)(VsB + (o0 ^ 32));  // keys of kn=2kn2+1
                acc[nt][0] = __builtin_amdgcn_mfma_f32_16x16x32_bf16(av.s, b8[0][kn2], acc[nt][0], 0, 0, 0);
                acc[nt][1] = __builtin_amdgcn_mfma_f32_16x16x32_bf16(av.s, b8[1][kn2], acc[nt][1], 0, 0, 0);
            }
        }
        __builtin_amdgcn_s_setprio(0);
    }

    // row-sum: combine the 4 quads (same q=l15 across quads)
#pragma unroll
    for (int qs = 0; qs < 2; qs++) {
        l_acc[qs] += __shfl_xor(l_acc[qs], 16);
        l_acc[qs] += __shfl_xor(l_acc[qs], 32);
    }

    if (!split) {
        float rl[2] = {1.f / l_acc[0], 1.f / l_acc[1]};
#pragma unroll
        for (int qs = 0; qs < 2; qs++) {
            int s = q0 + wave * 32 + qs * 16 + l15;
            float* orow = &ob[((size_t)(comp * 16 + h) * 2048 + s) * 128 + quad * 4];
#pragma unroll
            for (int nt = 0; nt < 8; nt++) {
                f32x4 v;
#pragma unroll
                for (int r = 0; r < 4; r++) v[r] = acc[nt][qs][r] * rl[qs];
                *(f32x4*)&orow[nt * 16] = v;
            }
        }
    } else {
        // unnormalized partials; half0 -> ob rows, half1 -> op1 (rows s-1024)
#pragma unroll
        for (int qs = 0; qs < 2; qs++) {
            int s = q0 + wave * 32 + qs * 16 + l15;
            float* orow = (half == 0)
                ? &ob[((size_t)(comp * 16 + h) * 2048 + s) * 128 + quad * 4]
                : &op1[((size_t)(comp * 16 + h) * 1024 + (s - 1024)) * 128 + quad * 4];
#pragma unroll
            for (int nt = 0; nt < 8; nt++) {
                f32x4 v;
#pragma unroll
                for (int r = 0; r < 4; r++) v[r] = acc[nt][qs][r];
                *(f32x4*)&orow[nt * 16] = v;
            }
        }
        float* lbp = ((half == 0) ? lb0 : lb1) + (comp * 16 + h) * 1024;
        if (quad == 0) {
#pragma unroll
            for (int qs = 0; qs < 2; qs++) {
                int s = q0 + wave * 32 + qs * 16 + l15;
                lbp[s - 1024] = l_acc[qs];
            }
        }
    }
}

// ---------------- combine: merge key-split partials, A1 - lam*A2, groupnorm ----
__global__ __launch_bounds__(256) void combine_kernel(const float* __restrict__ ob,
                                                      const float* __restrict__ op1,
                                                      const float* __restrict__ lb0,
                                                      const float* __restrict__ lb1,
                                                      const float* __restrict__ lq1,
                                                      const float* __restrict__ lk1,
                                                      const float* __restrict__ lq2,
                                                      const float* __restrict__ lk2,
                                                      const float* __restrict__ gamma,
                                                      const float* __restrict__ beta,
                                                      u16* __restrict__ attn) {
    const int tid = threadIdx.x, wave = tid >> 6, lane = tid & 63;
    const int row = blockIdx.x * 4 + wave;  // 0..32767
    const int s = row >> 4, h = row & 15;
    const float lambda_init = 0.8f - 0.6f * __expf(-3.6f);
    const int d0 = lane * 2;
    const bool sp = (s >= 1024);
    float r1 = 1.f, r2 = 1.f;
    if (sp) {
        int i1 = h * 1024 + (s - 1024);
        int i2 = (16 + h) * 1024 + (s - 1024);
        r1 = 1.f / (lb0[i1] + lb1[i1]);
        r2 = 1.f / (lb0[i2] + lb1[i2]);
    }
    float vals[2];
#pragma unroll
    for (int j = 0; j < 2; j++) {
        int d = d0 + j;
        float a1 = ob[((h) * 2048 + s) * 128 + d];
        float a2 = ob[((16 + h) * 2048 + s) * 128 + d];
        if (sp) {
            a1 = (a1 + op1[((size_t)h * 1024 + (s - 1024)) * 128 + d]) * r1;
            a2 = (a2 + op1[((size_t)(16 + h) * 1024 + (s - 1024)) * 128 + d]) * r2;
        }
        float lam = __expf(lq1[d] * lk1[d]) - __expf(lq2[d] * lk2[d]) + lambda_init;
        vals[j] = a1 - lam * a2;
    }
    float sum = vals[0] + vals[1];
    float sq = vals[0] * vals[0] + vals[1] * vals[1];
#pragma unroll
    for (int off = 1; off < 64; off <<= 1) {
        sum += __shfl_xor(sum, off);
        sq += __shfl_xor(sq, off);
    }
    float mu = sum * (1.f / 128.f);
    float var = sq * (1.f / 128.f) - mu * mu;
    float rinv = rsqrtf(var + 1e-5f);
    float osc = 1.f - lambda_init;
#pragma unroll
    for (int j = 0; j < 2; j++) {
        int d = d0 + j;
        float g = gamma[h * 128 + d], b = beta[h * 128 + d];
        float v = ((vals[j] - mu) * rinv * g + b) * osc;
        attn[s * 2048 + h * 128 + d] = f2bf(v);
    }
}

// ---------------- launch ----------------
extern "C" void kernel_launch(void* const* d_in, const int* in_sizes, int n_in,
                              void* d_out, int out_size, void* d_ws, size_t ws_size,
                              hipStream_t stream) {
    (void)in_sizes; (void)n_in; (void)out_size; (void)ws_size;
    const float* x    = (const float*)d_in[0];
    const float* Wqkv = (const float*)d_in[1];
    const float* Wo   = (const float*)d_in[2];
    const float* lq1  = (const float*)d_in[3];
    const float* lk1  = (const float*)d_in[4];
    const float* lq2  = (const float*)d_in[5];
    const float* lk2  = (const float*)d_in[6];
    const float* gam  = (const float*)d_in[7];
    const float* bet  = (const float*)d_in[8];
    float* out = (float*)d_out;

    char* ws = (char*)d_ws;
    u16*   xb    = (u16*)(ws);                       // [0,8M)   x bf16; reused for attn out
    u16*   wqkvb = (u16*)(ws + (size_t)(8 << 20));   // [8,32M)  W_qkv bf16
    float* ob    = (float*)(ws + (size_t)(8 << 20)); // [8,40M)  O / half0 partials (after W_qkv consumed)
    u16*   wob   = (u16*)(ws + (size_t)(40 << 20));  // [40,48M) W_o bf16
    u16*   qb    = (u16*)(ws + (size_t)(48 << 20));  // [48,56M)
    u16*   kb    = (u16*)(ws + (size_t)(56 << 20));  // [56,64M)
    u16*   vb    = (u16*)(ws + (size_t)(64 << 20));  // [64,72M)
    u16*   vT    = (u16*)(ws + (size_t)(72 << 20));  // [72,80M)
    u16*   attn  = (u16*)(ws);                       // reuse xb region
    float* lb0   = (float*)(ws + (size_t)(64 << 20));            // 128KB (vb region, free post-transpose)
    float* lb1   = (float*)(ws + (size_t)(64 << 20) + (1 << 17)); // 128KB
    float* op1   = out;  // d_out as scratch for half1 partials (16MB, exact fit);
                         // consumed by combine before the final GEMM overwrites it

    // 1. fused casts: x (4096 blocks) | W_qkv (12288) | W_o (4096)
    cast3_kernel<<<20480, 256, 0, stream>>>(x, xb, Wqkv, wqkvb, Wo, wob);
    // 2. QKV GEMM with scatter epilogue (q pre-scaled by 0.125*log2e)
    gemm_bt<128, 128, 1, 3><<<dim3(48, 16), 256, 0, stream>>>(
        xb, wqkvb, 2048, 6144, 2048, nullptr, qb, kb, vb);
    // 3. V transpose per head
    transpose_v<<<dim3(32, 16), 256, 0, stream>>>(vb, vT);
    // 4. flash attention, key-split load-balanced (768 blocks = 3/CU)
    attn_kernel<<<768, 256, 0, stream>>>(qb, kb, vT, ob, op1, lb0, lb1);
    // 5. combine (merge partials) + groupnorm -> bf16
    combine_kernel<<<8192, 256, 0, stream>>>(ob, op1, lb0, lb1,
                                             lq1, lk1, lq2, lk2, gam, bet, attn);
    // 6. output GEMM -> fp32 (128x64 tiles: 512 blocks = 2/CU)
    gemm_bt<128, 64, 0, 2><<<dim3(32, 16), 256, 0, stream>>>(
        attn, wob, 2048, 2048, 2048, out, nullptr, nullptr, nullptr);
}

// Round 9
// 275.698 us; speedup vs baseline: 1.0782x; 1.0782x over previous
//
#include <hip/hip_runtime.h>

typedef short short8 __attribute__((ext_vector_type(8)));
typedef float f32x4 __attribute__((ext_vector_type(4)));
typedef unsigned short u16;
typedef u16 u16x8 __attribute__((ext_vector_type(8)));
typedef u16 u16x4 __attribute__((ext_vector_type(4)));

__device__ static inline u16 f2bf(float f) {
    union { float f; unsigned u; } v; v.f = f;
    unsigned r = v.u + 0x7fffu + ((v.u >> 16) & 1u);
    return (u16)(r >> 16);
}

// packed f32x2 -> bf16x2 (RNE), low16 = cvt(a), high16 = cvt(b)
__device__ static inline unsigned cvt_pk_bf16(float a, float b) {
    unsigned r;
    asm("v_cvt_pk_bf16_f32 %0, %1, %2" : "=v"(r) : "v"(a), "v"(b));
    return r;
}

// async global->LDS, 16B per lane; LDS dest must be wave-uniform base + lane*16
__device__ static inline void gload16(const u16* g, u16* l) {
    __builtin_amdgcn_global_load_lds(
        (const __attribute__((address_space(1))) unsigned int*)g,
        (__attribute__((address_space(3))) unsigned int*)l,
        16, 0, 0);
}

// ---------------- fused cast fp32 -> bf16 for x / W_qkv / W_o --------------------
__global__ __launch_bounds__(256) void cast3_kernel(const float* __restrict__ xa,
                                                    u16* __restrict__ xo,
                                                    const float* __restrict__ wa,
                                                    u16* __restrict__ wo,
                                                    const float* __restrict__ oa,
                                                    u16* __restrict__ oo) {
    const int bid = blockIdx.x;
    const float* in;
    u16* out;
    int b;
    if (bid < 4096)        { in = xa; out = xo; b = bid; }
    else if (bid < 16384)  { in = wa; out = wo; b = bid - 4096; }
    else                   { in = oa; out = oo; b = bid - 16384; }
    int i = (b * 256 + threadIdx.x) * 4;
    f32x4 v = *(const f32x4*)&in[i];
    union { unsigned w[2]; u16x4 s; } o;
    o.w[0] = cvt_pk_bf16(v[0], v[1]);
    o.w[1] = cvt_pk_bf16(v[2], v[3]);
    *(u16x4*)&out[i] = o.s;
}

// ---------------- QKV GEMM: 256x256 tile, 4-phase/K-tile counted-vmcnt ----------
// Faithful port of the 8-phase-template mechanism (phases here = 4 per K-tile,
// 8 per unrolled 2-tile pair):
//  * raw s_barrier + counted vmcnt(4) (NEVER __syncthreads -> no vmcnt(0) drain)
//  * global C-quadrant phases (0,0)->(0,1)->(1,1)->(1,0): all 8 waves work one
//    128x128 quadrant, so LDS unit consumption is STAGGERED:
//      phase0 needs A0,B0 | phase1 B1 | phase2 A1 | phase3 (reuse B0)
//  * units A0,B0,B1,A1 (128 rows x 64 k, 16KB) staged one per phase for tile
//    t+1 into buf^1; vmcnt(4) before phases 0,1,2 leaves 2 units in flight.
//  * proven XOR swizzle (slot = g ^ (row&7)) via pre-swizzled global source +
//    linear LDS dest (global_load_lds contract); conflict-free b128 reads.
__global__ __launch_bounds__(512, 2) void gemm_qkv8(const u16* __restrict__ A,
                                                    const u16* __restrict__ B,
                                                    u16* __restrict__ Qo,
                                                    u16* __restrict__ Ko,
                                                    u16* __restrict__ Vo) {
    constexpr int K = 2048, NTL = K / 64;
    __shared__ u16 lds[2][4][128 * 64];  // [dbuf][unit A0,B0,B1,A1][row][k]
    const int tid = threadIdx.x;
    const int lane = tid & 63, wave = tid >> 6;
    const int quad = lane >> 4, l15 = lane & 15;
    const int rs = wave >> 1, ch = wave & 1;  // row-strip (4) x col-half (2)
    const int m0 = blockIdx.y * 256, n0 = blockIdx.x * 256;

    // staging sources: pre-swizzled global (slot s8 holds kgroup g = s8^(row&7))
    const u16* gsrc[4][2];
#pragma unroll
    for (int j = 0; j < 2; j++) {
        int s = j * 512 + tid;
        int row = s >> 3;
        int g = (s & 7) ^ (row & 7);
        gsrc[0][j] = &A[(size_t)(m0 + row) * K + g * 8];
        gsrc[1][j] = &B[(size_t)(n0 + row) * K + g * 8];
        gsrc[2][j] = &B[(size_t)(n0 + 128 + row) * K + g * 8];
        gsrc[3][j] = &A[(size_t)(m0 + 128 + row) * K + g * 8];
    }
    const int ldst = wave * 512;  // element offset; + j*4096

    // loop-invariant fragment byte-offsets within a 16KB unit
    int offA[2][2], offB[4][2];
#pragma unroll
    for (int mf = 0; mf < 2; mf++)
#pragma unroll
        for (int ku = 0; ku < 2; ku++) {
            int lr = rs * 32 + mf * 16 + l15;
            offA[mf][ku] = lr * 128 + (((ku * 4 + quad) ^ (lr & 7)) * 16);
        }
#pragma unroll
    for (int nf = 0; nf < 4; nf++)
#pragma unroll
        for (int ku = 0; ku < 2; ku++) {
            int lb = ch * 64 + nf * 16 + l15;
            offB[nf][ku] = lb * 128 + (((ku * 4 + quad) ^ (lb & 7)) * 16);
        }

    f32x4 acc[2][2][2][4] = {};  // [MH][NH][mf][nf]
    short8 af[2][2], bf[4][2];

    // prologue: stage tile 0 (units in consumption order; no drain needed --
    // first phase's vmcnt(4) covers U0,U1)
#pragma unroll
    for (int u = 0; u < 4; u++) {
        gload16(gsrc[u][0], &lds[0][u][ldst]);
        gload16(gsrc[u][1], &lds[0][u][ldst + 4096]);
    }

#define LOAD_A(MH)                                                             \
    {                                                                          \
        const char* ub = Lp + (MH ? 3 : 0) * 16384;                            \
        _Pragma("unroll") for (int mf = 0; mf < 2; mf++)                       \
            _Pragma("unroll") for (int ku = 0; ku < 2; ku++)                   \
                af[mf][ku] = *(const short8*)(ub + offA[mf][ku]);              \
    }
#define LOAD_B(NH)                                                             \
    {                                                                          \
        const char* ub = Lp + (NH ? 2 : 1) * 16384;                            \
        _Pragma("unroll") for (int nf = 0; nf < 4; nf++)                       \
            _Pragma("unroll") for (int ku = 0; ku < 2; ku++)                   \
                bf[nf][ku] = *(const short8*)(ub + offB[nf][ku]);              \
    }
#define MMA(MH, NH)                                                            \
    __builtin_amdgcn_s_setprio(1);                                             \
    _Pragma("unroll") for (int mf = 0; mf < 2; mf++)                           \
        _Pragma("unroll") for (int nf = 0; nf < 4; nf++)                       \
            _Pragma("unroll") for (int ku = 0; ku < 2; ku++)                   \
                acc[MH][NH][mf][nf] = __builtin_amdgcn_mfma_f32_16x16x32_bf16( \
                    af[mf][ku], bf[nf][ku], acc[MH][NH][mf][nf], 0, 0, 0);     \
    __builtin_amdgcn_s_setprio(0);
#define WAITBAR                                                                \
    asm volatile("s_waitcnt vmcnt(4)" ::: "memory");                           \
    __builtin_amdgcn_s_barrier();                                              \
    asm volatile("" ::: "memory");
#define STAGE(u)                                                               \
    gload16(gsrc[u][0] + ko, &lds[pn][u][ldst]);                               \
    gload16(gsrc[u][1] + ko, &lds[pn][u][ldst + 4096]);

    for (int t = 0; t < NTL; t++) {
        const int p = t & 1, pn = p ^ 1;
        const int ko = (t + 1 < NTL) ? (t + 1) * 64 : t * 64;  // clamp: uniform vmcnt
        const char* Lp = (const char*)lds[p];

        // phase 0: quadrant (0,0); vmcnt(4) -> U0,U1(t) landed
        WAITBAR; STAGE(0);
        LOAD_A(0); LOAD_B(0); MMA(0, 0);
        // phase 1: (0,1); vmcnt(4) -> U2(t)=B1 landed
        WAITBAR; STAGE(1);
        LOAD_B(1); MMA(0, 1);
        // phase 2: (1,1); vmcnt(4) -> U3(t)=A1 landed
        WAITBAR; STAGE(2);
        LOAD_A(1); MMA(1, 1);
        // phase 3: (1,0); no wait/barrier (re-reads B0, long published)
        STAGE(3);
        LOAD_B(0); MMA(1, 0);
    }
#undef LOAD_A
#undef LOAD_B
#undef MMA
#undef WAITBAR
#undef STAGE

    // epilogue: scatter to Q/K/V (comp uniform per block)
    const int comp = n0 >> 11;
    u16* dst = (comp == 0) ? Qo : ((comp == 1) ? Ko : Vo);
    const float sc = (comp == 0) ? 0.18033688f : 1.0f;  // 0.125*log2(e)
#pragma unroll
    for (int MH = 0; MH < 2; MH++)
#pragma unroll
        for (int NH = 0; NH < 2; NH++)
#pragma unroll
            for (int mf = 0; mf < 2; mf++)
#pragma unroll
                for (int nf = 0; nf < 4; nf++)
#pragma unroll
                    for (int r = 0; r < 4; r++) {
                        int row = m0 + MH * 128 + rs * 32 + mf * 16 + quad * 4 + r;
                        int d = (n0 & 2047) + NH * 128 + ch * 64 + nf * 16 + l15;
                        int h = d >> 7, dd = d & 127;
                        dst[((h * 2048) + row) * 128 + dd] =
                            f2bf(acc[MH][NH][mf][nf][r] * sc);
                    }
}

// ---------------- GEMM: C = A(MxK) * B(NxK)^T, bf16 in, fp32 acc ----------------
// Register-staged prefetch + XOR bank-swizzle (verified round-5 config).
// Used for the output GEMM only.
template <int BM, int BN, int MODE, int MINW>
__global__ __launch_bounds__(256, MINW) void gemm_bt(const u16* __restrict__ A,
                                                     const u16* __restrict__ B,
                                                     int M, int N, int K,
                                                     float* __restrict__ C,
                                                     u16* __restrict__ Qo,
                                                     u16* __restrict__ Ko,
                                                     u16* __restrict__ Vo) {
    constexpr int APT = BM * 4 / 256;
    constexpr int BPT = BN * 4 / 256;
    constexpr int MT = BM / 32, NT = BN / 32;
    __shared__ u16 As[BM * 32];
    __shared__ u16 Bs[BN * 32];
    const int tid  = threadIdx.x;
    const int lane = tid & 63, wave = tid >> 6;
    const int quad = lane >> 4, l15 = lane & 15;
    const int wm = wave >> 1, wn = wave & 1;
    const int m0 = blockIdx.y * BM;
    const int n0 = blockIdx.x * BN;

    f32x4 acc[MT][NT] = {};

    const u16* aga[APT];
    const u16* bga[BPT];
#pragma unroll
    for (int i = 0; i < APT; i++) {
        int s = tid + i * 256, r = s >> 2;
        int kg = (s & 3) ^ ((r >> 1) & 3);
        aga[i] = &A[(size_t)(m0 + r) * K + kg * 8];
    }
#pragma unroll
    for (int i = 0; i < BPT; i++) {
        int s = tid + i * 256, r = s >> 2;
        int kg = (s & 3) ^ ((r >> 1) & 3);
        bga[i] = &B[(size_t)(n0 + r) * K + kg * 8];
    }

    u16x8 ast[APT], bst[BPT];
#pragma unroll
    for (int i = 0; i < APT; i++) ast[i] = *(const u16x8*)aga[i];
#pragma unroll
    for (int i = 0; i < BPT; i++) bst[i] = *(const u16x8*)bga[i];

    for (int k0 = 0; k0 < K; k0 += 32) {
        if (k0) __syncthreads();
#pragma unroll
        for (int i = 0; i < APT; i++) *(u16x8*)&As[(tid + i * 256) * 8] = ast[i];
#pragma unroll
        for (int i = 0; i < BPT; i++) *(u16x8*)&Bs[(tid + i * 256) * 8] = bst[i];
        __syncthreads();
        if (k0 + 32 < K) {
#pragma unroll
            for (int i = 0; i < APT; i++) ast[i] = *(const u16x8*)(aga[i] + k0 + 32);
#pragma unroll
            for (int i = 0; i < BPT; i++) bst[i] = *(const u16x8*)(bga[i] + k0 + 32);
        }

        short8 af[MT], bf[NT];
#pragma unroll
        for (int mt = 0; mt < MT; mt++) {
            int row = wm * (BM / 2) + mt * 16 + l15;
            int slot = row * 4 + (quad ^ ((row >> 1) & 3));
            af[mt] = *(const short8*)&As[slot * 8];
        }
#pragma unroll
        for (int nt = 0; nt < NT; nt++) {
            int row = wn * (BN / 2) + nt * 16 + l15;
            int slot = row * 4 + (quad ^ ((row >> 1) & 3));
            bf[nt] = *(const short8*)&Bs[slot * 8];
        }
#pragma unroll
        for (int mt = 0; mt < MT; mt++)
#pragma unroll
            for (int nt = 0; nt < NT; nt++)
                acc[mt][nt] = __builtin_amdgcn_mfma_f32_16x16x32_bf16(af[mt], bf[nt], acc[mt][nt], 0, 0, 0);
    }

    if (MODE == 0) {
#pragma unroll
        for (int mt = 0; mt < MT; mt++)
#pragma unroll
            for (int nt = 0; nt < NT; nt++)
#pragma unroll
                for (int r = 0; r < 4; r++) {
                    int row = m0 + wm * (BM / 2) + mt * 16 + quad * 4 + r;
                    int col = n0 + wn * (BN / 2) + nt * 16 + l15;
                    C[(size_t)row * N + col] = acc[mt][nt][r];
                }
    } else {
        const int comp = n0 >> 11, h = (n0 >> 7) & 15;
        u16* dst = (comp == 0) ? Qo : ((comp == 1) ? Ko : Vo);
        const float sc = (comp == 0) ? 0.18033688f : 1.0f;
#pragma unroll
        for (int mt = 0; mt < MT; mt++)
#pragma unroll
            for (int nt = 0; nt < NT; nt++)
#pragma unroll
                for (int r = 0; r < 4; r++) {
                    int row = m0 + wm * (BM / 2) + mt * 16 + quad * 4 + r;
                    int d = wn * (BN / 2) + nt * 16 + l15;
                    dst[((h * 2048) + row) * 128 + d] = f2bf(acc[mt][nt][r] * sc);
                }
    }
}

// ---------------- per-head V transpose: vb[h][s][d] -> vT[h][d][s] ----------------
__global__ __launch_bounds__(256) void transpose_v(const u16* __restrict__ vb,
                                                   u16* __restrict__ vT) {
    __shared__ u16 T[64 * 136];
    const int s0 = blockIdx.x * 64, h = blockIdx.y;
    const int tid = threadIdx.x;
#pragma unroll
    for (int i = 0; i < 4; i++) {
        int c = tid + i * 256;
        int s = c >> 4, dch = c & 15;
        *(u16x8*)&T[s * 136 + dch * 8] =
            *(const u16x8*)&vb[((h * 2048) + s0 + s) * 128 + dch * 8];
    }
    __syncthreads();
#pragma unroll
    for (int i = 0; i < 4; i++) {
        int c = tid + i * 256;
        int d = c >> 3, sch = c & 7;
        u16x8 o;
#pragma unroll
        for (int j = 0; j < 8; j++) o[j] = T[(sch * 8 + j) * 136 + d];
        *(u16x8*)&vT[((h * 128) + d) * 2048 + s0 + sch * 8] = o;
    }
}

// ---------------- flash attention, S^T formulation (round-5 verified) -----------
__global__ __launch_bounds__(256, 2) void attn_kernel(const u16* __restrict__ qb,
                                                      const u16* __restrict__ kb,
                                                      const u16* __restrict__ vT,
                                                      float* __restrict__ ob) {
    const int bid = blockIdx.x;
    const int h = bid & 15;
    const int comp = (bid >> 4) & 1;
    const int j = bid >> 5;                       // 0..15
    const int J = (j < 8) ? (2 * j + 1) : (30 - 2 * j);  // pairs (j,j+8) sum to 15
    const int nkt = 2 * J + 2;
    const int q0 = J * 128;
    const int tid = threadIdx.x, lane = tid & 63, wave = tid >> 6;
    const int quad = lane >> 4, l15 = lane & 15;
    const int qh = quad >> 1, ql = quad & 1;

    __shared__ u16 Ks[64 * 64];    // [key][dim-chunk swizzled]  (this comp)
    __shared__ u16 VsT[128 * 64];  // [dim][key-chunk swizzled]
    const char* KsB = (const char*)Ks;
    const char* VsB = (const char*)VsT;

    const u16* kb_h = &kb[(size_t)h * 2048 * 128 + comp * 64];
    const u16* vT_h = &vT[(size_t)h * 128 * 2048];

    // staging global addresses
    const int c1 = tid, c2 = tid + 256;
    const int k1key = c1 >> 3, k1dc = ((c1 & 7) ^ k1key) & 7;
    const int k2key = c2 >> 3, k2dc = ((c2 & 7) ^ k2key) & 7;
    const u16* kaddr1 = &kb_h[k1key * 128 + k1dc * 8];
    const u16* kaddr2 = &kb_h[k2key * 128 + k2dc * 8];
    const u16* vaddr[4];
#pragma unroll
    for (int i = 0; i < 4; i++) {
        int c = tid + i * 256;
        int dim = c >> 3, kc = ((c & 7) ^ dim) & 7;
        vaddr[i] = &vT_h[dim * 2048 + kc * 8];
    }

    // loop-invariant LDS read byte-offsets.
    const int koff0 = l15 * 128 + ((quad ^ l15) & 7) * 16;
    const int koff1 = l15 * 128 + (((quad + 4) ^ l15) & 7) * 16;
    int vbo[8][2];
#pragma unroll
    for (int nt = 0; nt < 8; nt++) {
        int dim = nt * 16 + l15;
        int base = dim * 128 + ((qh ^ dim) & 7) * 16 + ql * 8;
        vbo[nt][0] = base;
        vbo[nt][1] = base ^ 64;
    }

    // Q fragments as MFMA B-operand: B[n=q=l15][k=dim=quad*8+j]
    short8 aq[2][2];
#pragma unroll
    for (int qs = 0; qs < 2; qs++)
#pragma unroll
        for (int ks = 0; ks < 2; ks++) {
            int qrow = q0 + wave * 32 + qs * 16 + l15;
            aq[qs][ks] = *(const short8*)
                &qb[((h * 2048) + qrow) * 128 + comp * 64 + ks * 32 + quad * 8];
        }

    float l_acc[2] = {0.f, 0.f};
    f32x4 acc[8][2] = {};  // O^T: [dim-tile nt][q-subtile]; rows=dim, cols=q

    u16x8 kst0, kst1, vst[4];
    kst0 = *(const u16x8*)kaddr1;
    kst1 = *(const u16x8*)kaddr2;
#pragma unroll
    for (int i = 0; i < 4; i++) vst[i] = *(const u16x8*)vaddr[i];
    const u16* kp1 = kaddr1 + 8192;
    const u16* kp2 = kaddr2 + 8192;
    const u16* vp[4];
#pragma unroll
    for (int i = 0; i < 4; i++) vp[i] = vaddr[i] + 64;

    for (int kt = 0; kt < nkt; kt++) {
        *(u16x8*)&Ks[c1 * 8] = kst0;
        *(u16x8*)&Ks[c2 * 8] = kst1;
#pragma unroll
        for (int i = 0; i < 4; i++) *(u16x8*)&VsT[(tid + i * 256) * 8] = vst[i];
        __syncthreads();

        if (kt + 1 < nkt) {
            kst0 = *(const u16x8*)kp1; kp1 += 8192;
            kst1 = *(const u16x8*)kp2; kp2 += 8192;
#pragma unroll
            for (int i = 0; i < 4; i++) { vst[i] = *(const u16x8*)vp[i]; vp[i] += 64; }
        }

        // K fragments once per tile (shared by both q-subtiles)
        short8 kf[4][2];
#pragma unroll
        for (int kn = 0; kn < 4; kn++) {
            kf[kn][0] = *(const short8*)(KsB + (koff0 + kn * 2048));
            kf[kn][1] = *(const short8*)(KsB + (koff1 + kn * 2048));
        }

        // S^T = K*Q^T; exponentiate in-register; pack FULL-K PV B-fragments
        short8 b8[2][2];  // [qs][kn2]: slots 0..3 <- kn=2kn2, 4..7 <- kn=2kn2+1
#pragma unroll
        for (int qs = 0; qs < 2; qs++) {
#pragma unroll
            for (int kn2 = 0; kn2 < 2; kn2++) {
                f32x4 sa = {}, sb = {};
                sa = __builtin_amdgcn_mfma_f32_16x16x32_bf16(kf[2 * kn2][0], aq[qs][0], sa, 0, 0, 0);
                sa = __builtin_amdgcn_mfma_f32_16x16x32_bf16(kf[2 * kn2][1], aq[qs][1], sa, 0, 0, 0);
                sb = __builtin_amdgcn_mfma_f32_16x16x32_bf16(kf[2 * kn2 + 1][0], aq[qs][0], sb, 0, 0, 0);
                sb = __builtin_amdgcn_mfma_f32_16x16x32_bf16(kf[2 * kn2 + 1][1], aq[qs][1], sb, 0, 0, 0);
                if (kt >= nkt - 2) {  // diagonal region: causal mask
                    int q = q0 + wave * 32 + qs * 16 + l15;
                    int kb0 = kt * 64 + kn2 * 32 + quad * 4;
#pragma unroll
                    for (int r = 0; r < 4; r++) {
                        if (kb0 + r > q) sa[r] = -1e30f;
                        if (kb0 + 16 + r > q) sb[r] = -1e30f;
                    }
                }
                float p0 = exp2f(sa[0]), p1 = exp2f(sa[1]), p2 = exp2f(sa[2]), p3 = exp2f(sa[3]);
                float p4 = exp2f(sb[0]), p5 = exp2f(sb[1]), p6 = exp2f(sb[2]), p7 = exp2f(sb[3]);
                l_acc[qs] += ((p0 + p1) + (p2 + p3)) + ((p4 + p5) + (p6 + p7));
                union { unsigned w[4]; short8 s; } pw;
                pw.w[0] = cvt_pk_bf16(p0, p1);
                pw.w[1] = cvt_pk_bf16(p2, p3);
                pw.w[2] = cvt_pk_bf16(p4, p5);
                pw.w[3] = cvt_pk_bf16(p6, p7);
                b8[qs][kn2] = pw.s;
            }
        }

        // PV: O^T[d][q] += V^T * P^T, full-K (32 keys per MFMA).
        __builtin_amdgcn_s_setprio(1);
#pragma unroll
        for (int nt = 0; nt < 8; nt++) {
#pragma unroll
            for (int kn2 = 0; kn2 < 2; kn2++) {
                union { u16x4 h4[2]; short8 s; } av;
                int o0 = vbo[nt][kn2];
                av.h4[0] = *(const u16x4*)(VsB + o0);         // keys of kn=2kn2
                av.h4[1] = *(const u16x4*)(VsB + (o0 ^ 32));  // keys of kn=2kn2+1
                acc[nt][0] = __builtin_amdgcn_mfma_f32_16x16x32_bf16(av.s, b8[0][kn2], acc[nt][0], 0, 0, 0);
                acc[nt][1] = __builtin_amdgcn_mfma_f32_16x16x32_bf16(av.s, b8[1][kn2], acc[nt][1], 0, 0, 0);
            }
        }
        __builtin_amdgcn_s_setprio(0);
        __syncthreads();
    }

    // row-sum: combine the 4 quads (same q=l15 across quads)
#pragma unroll
    for (int qs = 0; qs < 2; qs++) {
        l_acc[qs] += __shfl_xor(l_acc[qs], 16);
        l_acc[qs] += __shfl_xor(l_acc[qs], 32);
    }
    float rl[2] = {1.f / l_acc[0], 1.f / l_acc[1]};

    // epilogue: O^T -> ob[comp][h][s][d] fp32 (dwordx4 per lane along d)
#pragma unroll
    for (int qs = 0; qs < 2; qs++) {
        int s = q0 + wave * 32 + qs * 16 + l15;
        float* orow = &ob[((size_t)(comp * 16 + h) * 2048 + s) * 128 + quad * 4];
#pragma unroll
        for (int nt = 0; nt < 8; nt++) {
            f32x4 v;
#pragma unroll
            for (int r = 0; r < 4; r++) v[r] = acc[nt][qs][r] * rl[qs];
            *(f32x4*)&orow[nt * 16] = v;
        }
    }
}

// ---------------- combine: out = A1 - lam*A2, groupnorm, scale, -> bf16 ----------
__global__ __launch_bounds__(256) void combine_kernel(const float* __restrict__ ob,
                                                      const float* __restrict__ lq1,
                                                      const float* __restrict__ lk1,
                                                      const float* __restrict__ lq2,
                                                      const float* __restrict__ lk2,
                                                      const float* __restrict__ gamma,
                                                      const float* __restrict__ beta,
                                                      u16* __restrict__ attn) {
    const int tid = threadIdx.x, wave = tid >> 6, lane = tid & 63;
    const int row = blockIdx.x * 4 + wave;  // 0..32767
    const int s = row >> 4, h = row & 15;
    const float lambda_init = 0.8f - 0.6f * __expf(-3.6f);
    const int d0 = lane * 2;
    float vals[2];
#pragma unroll
    for (int j = 0; j < 2; j++) {
        int d = d0 + j;
        float a1 = ob[((h)*2048 + s) * 128 + d];
        float a2 = ob[((16 + h) * 2048 + s) * 128 + d];
        float lam = __expf(lq1[d] * lk1[d]) - __expf(lq2[d] * lk2[d]) + lambda_init;
        vals[j] = a1 - lam * a2;
    }
    float sum = vals[0] + vals[1];
    float sq = vals[0] * vals[0] + vals[1] * vals[1];
#pragma unroll
    for (int off = 1; off < 64; off <<= 1) {
        sum += __shfl_xor(sum, off);
        sq += __shfl_xor(sq, off);
    }
    float mu = sum * (1.f / 128.f);
    float var = sq * (1.f / 128.f) - mu * mu;
    float rinv = rsqrtf(var + 1e-5f);
    float osc = 1.f - lambda_init;
#pragma unroll
    for (int j = 0; j < 2; j++) {
        int d = d0 + j;
        float g = gamma[h * 128 + d], b = beta[h * 128 + d];
        float v = ((vals[j] - mu) * rinv * g + b) * osc;
        attn[s * 2048 + h * 128 + d] = f2bf(v);
    }
}

// ---------------- launch ----------------
extern "C" void kernel_launch(void* const* d_in, const int* in_sizes, int n_in,
                              void* d_out, int out_size, void* d_ws, size_t ws_size,
                              hipStream_t stream) {
    (void)in_sizes; (void)n_in; (void)out_size; (void)ws_size;
    const float* x    = (const float*)d_in[0];
    const float* Wqkv = (const float*)d_in[1];
    const float* Wo   = (const float*)d_in[2];
    const float* lq1  = (const float*)d_in[3];
    const float* lk1  = (const float*)d_in[4];
    const float* lq2  = (const float*)d_in[5];
    const float* lk2  = (const float*)d_in[6];
    const float* gam  = (const float*)d_in[7];
    const float* bet  = (const float*)d_in[8];
    float* out = (float*)d_out;

    char* ws = (char*)d_ws;
    u16*   xb    = (u16*)(ws);                       // [0,8M)   x bf16; reused for attn out
    u16*   wqkvb = (u16*)(ws + (size_t)(8 << 20));   // [8,32M)  W_qkv bf16
    float* ob    = (float*)(ws + (size_t)(8 << 20)); // [8,40M)  A1/A2 fp32 (after W_qkv consumed)
    u16*   wob   = (u16*)(ws + (size_t)(40 << 20));  // [40,48M) W_o bf16
    u16*   qb    = (u16*)(ws + (size_t)(48 << 20));  // [48,56M)
    u16*   kb    = (u16*)(ws + (size_t)(56 << 20));  // [56,64M)
    u16*   vb    = (u16*)(ws + (size_t)(64 << 20));  // [64,72M)
    u16*   vT    = (u16*)(ws + (size_t)(72 << 20));  // [72,80M)
    u16*   attn  = (u16*)(ws);                       // reuse xb region

    // 1. fused casts: x (4096 blocks) | W_qkv (12288) | W_o (4096)
    cast3_kernel<<<20480, 256, 0, stream>>>(x, xb, Wqkv, wqkvb, Wo, wob);
    // 2. QKV GEMM: 256x256 counted-vmcnt 4-phase pipeline (192 blocks, 512 thr)
    gemm_qkv8<<<dim3(24, 8), 512, 0, stream>>>(xb, wqkvb, qb, kb, vb);
    // 3. V transpose per head
    transpose_v<<<dim3(32, 16), 256, 0, stream>>>(vb, vT);
    // 4. flash attention, S^T formulation (512 blocks: h | comp | J-paired)
    attn_kernel<<<512, 256, 0, stream>>>(qb, kb, vT, ob);
    // 5. combine + groupnorm -> bf16
    combine_kernel<<<8192, 256, 0, stream>>>(ob, lq1, lk1, lq2, lk2, gam, bet, attn);
    // 6. output GEMM -> fp32 (128x64 tiles: 512 blocks = 2/CU)
    gemm_bt<128, 64, 0, 2><<<dim3(32, 16), 256, 0, stream>>>(
        attn, wob, 2048, 2048, 2048, out, nullptr, nullptr, nullptr);
}